// Round 5
// baseline (1134.632 us; speedup 1.0000x reference)
//
#include <hip/hip_runtime.h>
#include <hip/hip_bf16.h>

#define E_TOTAL 800000
#define BM 128            // edges per block
#define WT 36             // xtile stride in floats (16B-aligned rows)

static constexpr float INV_SQRT3_C = 0.57735026918962576f;
// CS = A_SCALAR * (1/16 fc_w2 scale) * (0.25 final scale); A_VECTOR*INV_SQRT3 == A_SCALAR
static constexpr float CS = 0.0013810679320049758f;

typedef __attribute__((ext_vector_type(8)))  __bf16 bf16x8;
typedef __attribute__((ext_vector_type(8)))  short  s16x8;
typedef __attribute__((ext_vector_type(16))) float  f32x16;

union frag_u { s16x8 s; bf16x8 b; };

typedef __attribute__((address_space(3))) unsigned int lds_u32;
typedef const __attribute__((address_space(1))) unsigned int glb_u32;

__device__ __forceinline__ void split_bf16(float v, short& hi, short& lo) {
    unsigned u  = __float_as_uint(v);
    unsigned hb = (u + 0x7fffu + ((u >> 16) & 1u)) & 0xffff0000u;
    hi = (short)(hb >> 16);
    float r = v - __uint_as_float(hb);           // exact
    unsigned u2 = __float_as_uint(r);
    lo = (short)((u2 + 0x7fffu + ((u2 >> 16) & 1u)) >> 16);
}

// Pre-pass: split fc_w2 (256x256 f32, [k][n]) into pass-major fragment order:
// w2f[idx], idx = pass*65536 + kc*4096 + hl*2048 + g*1024 + nloc*8 + i
// where k = kc*16 + g*8 + i, n = pass*128 + nloc, hl picks hi/lo bf16.
// Flat-chunk view: chunk s = pass*16+kc lives at w2f + s*4096.
__global__ void split_w2_kernel(const float* __restrict__ w2, short* __restrict__ w2f) {
    const int idx  = blockIdx.x * 256 + threadIdx.x;   // 0 .. 131071
    const int i    = idx & 7;
    const int nloc = (idx >> 3) & 127;
    const int g    = (idx >> 10) & 1;
    const int hl   = (idx >> 11) & 1;
    const int kc   = (idx >> 12) & 15;
    const int pass = idx >> 16;
    const int k = kc * 16 + g * 8 + i;
    const int n = pass * 128 + nloc;
    short hi, lo;
    split_bf16(w2[k * 256 + n], hi, lo);
    w2f[idx] = hl ? lo : hi;
}

__global__ __launch_bounds__(256, 3)
void conv_mfma_kernel(const float* __restrict__ nf,     // (N, 32)
                      const int*   __restrict__ esrc,
                      const int*   __restrict__ edst,
                      const float* __restrict__ esh,    // (E, 4)
                      const float* __restrict__ escal,  // (E, 8)
                      const float* __restrict__ w1,     // (8, 256)
                      const short* __restrict__ w2f,    // pass-major frag hi/lo bf16
                      float* __restrict__ out)          // (N, 32)
{
    __shared__ __align__(16) char smem[45056];
    short* Bbuf  = (short*)smem;                 // 2 x 4096 shorts (16 KB) dbuf
    float* xtile = (float*)(smem + 16384);       // [128][36] f32 (18 KB)
    float* shtl  = (float*)(smem + 34816);       // [128][4]  f32 (2 KB)
    float* w1l   = (float*)(smem + 36864);       // [8][256]  f32 (8 KB)

    const int t  = threadIdx.x;
    const int l  = t & 63;
    const int wv = t >> 6;                       // wave id = 32-edge tile
    const int e0 = blockIdx.x * BM;

    auto stage = [&](int s, int buf) {           // stage flat chunk s into Bbuf[buf]
        const short* src = w2f + (size_t)s * 4096;
        short* dst = Bbuf + buf * 4096;
        #pragma unroll
        for (int r = 0; r < 2; ++r)
            __builtin_amdgcn_global_load_lds((glb_u32*)(src + r * 2048 + t * 8),
                                             (lds_u32*)(dst + r * 2048 + t * 8),
                                             16, 0, 0);
    };

    stage(0, 0);   // issue first B-chunk ASAP

    // ---- prologue: stage x, sh, w1 into LDS
    {
        const int e = t >> 1, h2 = t & 1;
        const int src = esrc[e0 + e];
        const float* xp = nf + (size_t)src * 32 + h2 * 16;
        float* dp = xtile + e * WT + h2 * 16;
        #pragma unroll
        for (int q = 0; q < 4; ++q)
            *reinterpret_cast<float4*>(dp + q * 4) =
                *reinterpret_cast<const float4*>(xp + q * 4);
        if (t < BM)
            *reinterpret_cast<float4*>(shtl + t * 4) =
                *reinterpret_cast<const float4*>(esh + (size_t)(e0 + t) * 4);
        *reinterpret_cast<float4*>(w1l + t * 8)     = *reinterpret_cast<const float4*>(w1 + t * 8);
        *reinterpret_cast<float4*>(w1l + t * 8 + 4) = *reinterpret_cast<const float4*>(w1 + t * 8 + 4);
    }

    // lane's escal row, pre-scaled by 0.5 (h = relu(escal@w1)*0.5 = relu((0.5*escal)@w1))
    const int erow = e0 + wv * 32 + (l & 31);
    float es[8];
    {
        const float4 a = *reinterpret_cast<const float4*>(escal + (size_t)erow * 8);
        const float4 b = *reinterpret_cast<const float4*>(escal + (size_t)erow * 8 + 4);
        es[0]=a.x*0.5f; es[1]=a.y*0.5f; es[2]=a.z*0.5f; es[3]=a.w*0.5f;
        es[4]=b.x*0.5f; es[5]=b.y*0.5f; es[6]=b.z*0.5f; es[7]=b.w*0.5f;
    }

    __syncthreads();   // w1l/xtile/shtl resident; stage(0) drained (vmcnt 0 at barrier)

    // h-fragment (B-operand): lane l holds h[k = kc*16+(l>>5)*8+i][edge = l&31]
    auto compute_A = [&](int kc, frag_u& fh, frag_u& fl) {
        const int hb = kc * 16 + (l >> 5) * 8;
        float hv[8];
        #pragma unroll
        for (int i2 = 0; i2 < 8; ++i2) hv[i2] = 0.f;
        #pragma unroll
        for (int b = 0; b < 8; ++b) {
            const float4 wa  = *reinterpret_cast<const float4*>(w1l + b * 256 + hb);
            const float4 wb4 = *reinterpret_cast<const float4*>(w1l + b * 256 + hb + 4);
            hv[0] = fmaf(es[b], wa.x,  hv[0]);
            hv[1] = fmaf(es[b], wa.y,  hv[1]);
            hv[2] = fmaf(es[b], wa.z,  hv[2]);
            hv[3] = fmaf(es[b], wa.w,  hv[3]);
            hv[4] = fmaf(es[b], wb4.x, hv[4]);
            hv[5] = fmaf(es[b], wb4.y, hv[5]);
            hv[6] = fmaf(es[b], wb4.z, hv[6]);
            hv[7] = fmaf(es[b], wb4.w, hv[7]);
        }
        #pragma unroll
        for (int i2 = 0; i2 < 8; ++i2) {
            const float v = fmaxf(hv[i2], 0.f);
            short hi, lo;
            split_bf16(v, hi, lo);
            fh.s[i2] = hi;
            fl.s[i2] = lo;
        }
    };

    frag_u Ahi, Alo;
    compute_A(0, Ahi, Alo);

    f32x16 acc[4];
    #pragma unroll
    for (int nt = 0; nt < 4; ++nt)
        #pragma unroll
        for (int q = 0; q < 16; ++q) acc[nt][q] = 0.f;

    const int bbase = (l >> 5) * 1024 + (l & 31) * 8;   // shorts: w2 frag for row n=l&31

    // ================= phase A: chunks 0..15 (n = 0..127 -> out_s) =================
    for (int s = 0; s < 16; ++s) {
        const int cur = s & 1;
        stage(s + 1, cur ^ 1);                 // s=15 stages chunk 16 (pass-1 kc0)
        frag_u Anh, Anl;
        compute_A((s + 1) & 15, Anh, Anl);
        const short* Bb = Bbuf + cur * 4096;
        #pragma unroll
        for (int nt = 0; nt < 4; ++nt) {
            frag_u Wh, Wl;
            Wh.s = *reinterpret_cast<const s16x8*>(Bb + bbase + nt * 256);
            Wl.s = *reinterpret_cast<const s16x8*>(Bb + 2048 + bbase + nt * 256);
            acc[nt] = __builtin_amdgcn_mfma_f32_32x32x16_bf16(Wh.b, Ahi.b, acc[nt], 0, 0, 0);
            acc[nt] = __builtin_amdgcn_mfma_f32_32x32x16_bf16(Wh.b, Alo.b, acc[nt], 0, 0, 0);
            acc[nt] = __builtin_amdgcn_mfma_f32_32x32x16_bf16(Wl.b, Ahi.b, acc[nt], 0, 0, 0);
        }
        Ahi = Anh; Alo = Anl;
        if (s < 15) __syncthreads();
    }

    // ---- lane-local epilogue setup: lane owns edge eg entirely
    const int eg  = wv * 32 + (l & 31);
    const int hi_ = l >> 5;                     // j-half: lanes 0-31 -> j 0-3, 32-63 -> 4-7
    const float* xr = xtile + eg * WT;
    const int dst = edst[e0 + eg];
    float* op = out + (size_t)dst * 32;
    const float s2  = shtl[eg * 4 + 0];
    const float v20 = shtl[eg * 4 + 1];
    const float v21 = shtl[eg * 4 + 2];
    const float v22 = shtl[eg * 4 + 3];

    // ---- epilogue pass 0: D reg r of acc[nt] holds n = nt*32 + (r&3) + 8*(r>>2) + 4*hi_
    // n = g*64 + u*8 + j  ->  j = (r&3)+4*hi_, q = nt*4+(r>>2), u = q&7, g = q>>3
    {
        float dv[8];
        #pragma unroll
        for (int u = 0; u < 8; ++u)
            dv[u] = xr[8 + u*3] * v20 + xr[8 + u*3 + 1] * v21 + xr[8 + u*3 + 2] * v22;
        float P0[4] = {0.f,0.f,0.f,0.f}, P1[4] = {0.f,0.f,0.f,0.f};
        #pragma unroll
        for (int nt = 0; nt < 4; ++nt)
            #pragma unroll
            for (int uu = 0; uu < 4; ++uu) {
                const int q = nt * 4 + uu, u = q & 7;
                const float s1u = xr[u];
                #pragma unroll
                for (int jj = 0; jj < 4; ++jj) {
                    const float w = acc[nt][uu * 4 + jj];
                    if (q < 8) P0[jj] = fmaf(s1u,   w, P0[jj]);   // group 0
                    else       P1[jj] = fmaf(dv[u], w, P1[jj]);   // group 1
                }
            }
        #pragma unroll
        for (int jj = 0; jj < 4; ++jj)
            atomicAdd(op + jj + 4 * hi_, CS * (s2 * P0[jj] + INV_SQRT3_C * P1[jj]));
    }

    #pragma unroll
    for (int nt = 0; nt < 4; ++nt)
        #pragma unroll
        for (int q = 0; q < 16; ++q) acc[nt][q] = 0.f;

    __syncthreads();   // chunk 16 resident in buf0; all buf1 reads of s=15 done

    // ================= phase B: chunks 16..31 (n = 128..255 -> out_v) =================
    for (int s = 16; s < 32; ++s) {
        const int cur = s & 1;
        if (s < 31) stage(s + 1, cur ^ 1);
        frag_u Anh, Anl;
        if (s < 31) compute_A((s + 1) & 15, Anh, Anl);
        const short* Bb = Bbuf + cur * 4096;
        #pragma unroll
        for (int nt = 0; nt < 4; ++nt) {
            frag_u Wh, Wl;
            Wh.s = *reinterpret_cast<const s16x8*>(Bb + bbase + nt * 256);
            Wl.s = *reinterpret_cast<const s16x8*>(Bb + 2048 + bbase + nt * 256);
            acc[nt] = __builtin_amdgcn_mfma_f32_32x32x16_bf16(Wh.b, Ahi.b, acc[nt], 0, 0, 0);
            acc[nt] = __builtin_amdgcn_mfma_f32_32x32x16_bf16(Wh.b, Alo.b, acc[nt], 0, 0, 0);
            acc[nt] = __builtin_amdgcn_mfma_f32_32x32x16_bf16(Wl.b, Ahi.b, acc[nt], 0, 0, 0);
        }
        if (s < 31) { Ahi = Anh; Alo = Anl; __syncthreads(); }
    }

    // ---- epilogue pass 1: local g0 -> w2-group (Q), g1 -> w3-group (R)
    {
        float Q[4]  = {0.f,0.f,0.f,0.f};
        float R0[4] = {0.f,0.f,0.f,0.f}, R1[4] = {0.f,0.f,0.f,0.f}, R2[4] = {0.f,0.f,0.f,0.f};
        #pragma unroll
        for (int nt = 0; nt < 4; ++nt)
            #pragma unroll
            for (int uu = 0; uu < 4; ++uu) {
                const int q = nt * 4 + uu, u = q & 7;
                const float s1u = xr[u];
                const float a0 = xr[8 + u*3], a1 = xr[8 + u*3 + 1], a2 = xr[8 + u*3 + 2];
                #pragma unroll
                for (int jj = 0; jj < 4; ++jj) {
                    const float w = acc[nt][uu * 4 + jj];
                    if (q < 8) Q[jj] = fmaf(s1u, w, Q[jj]);
                    else {
                        R0[jj] = fmaf(a0, w, R0[jj]);
                        R1[jj] = fmaf(a1, w, R1[jj]);
                        R2[jj] = fmaf(a2, w, R2[jj]);
                    }
                }
            }
        #pragma unroll
        for (int jj = 0; jj < 4; ++jj) {
            const int j = jj + 4 * hi_;
            atomicAdd(op + 8 + j * 3 + 0, CS * (Q[jj] * v20 + s2 * R0[jj]));
            atomicAdd(op + 8 + j * 3 + 1, CS * (Q[jj] * v21 + s2 * R1[jj]));
            atomicAdd(op + 8 + j * 3 + 2, CS * (Q[jj] * v22 + s2 * R2[jj]));
        }
    }
}

extern "C" void kernel_launch(void* const* d_in, const int* in_sizes, int n_in,
                              void* d_out, int out_size, void* d_ws, size_t ws_size,
                              hipStream_t stream) {
    const float* nf    = (const float*)d_in[0];
    const int*   esrc  = (const int*)d_in[1];
    const int*   edst  = (const int*)d_in[2];
    const float* esh   = (const float*)d_in[3];
    const float* escal = (const float*)d_in[4];
    const float* w1    = (const float*)d_in[5];
    const float* w2    = (const float*)d_in[6];
    float* out  = (float*)d_out;
    short* w2f  = (short*)d_ws;     // 256 KB

    hipMemsetAsync(d_out, 0, (size_t)out_size * sizeof(float), stream);
    split_w2_kernel<<<512, 256, 0, stream>>>(w2, w2f);
    conv_mfma_kernel<<<E_TOTAL / BM, 256, 0, stream>>>(
        nf, esrc, edst, esh, escal, w1, w2f, out);
}

// Round 8
// 899.683 us; speedup vs baseline: 1.2611x; 1.2611x over previous
//
#include <hip/hip_runtime.h>
#include <hip/hip_bf16.h>

#define E_TOTAL 800000
#define BM 128            // edges per block
#define NKC 16            // K chunks of 16 (K = 256)
#define WT 34             // wtile/xtile stride in floats

static constexpr float INV_SQRT3_C = 0.57735026918962576f;
// CS = A_SCALAR * (1/16 fc_w2 scale) * (0.25 final scale); A_VECTOR*INV_SQRT3 == A_SCALAR
static constexpr float CS = 0.0013810679320049758f;

typedef __attribute__((ext_vector_type(8)))  __bf16 bf16x8;
typedef __attribute__((ext_vector_type(8)))  short  s16x8;
typedef __attribute__((ext_vector_type(16))) float  f32x16;

union frag_u { s16x8 s; bf16x8 b; };

typedef __attribute__((address_space(3))) unsigned int lds_u32;
typedef const __attribute__((address_space(1))) unsigned int glb_u32;

__device__ __forceinline__ void split_bf16(float v, short& hi, short& lo) {
    unsigned u  = __float_as_uint(v);
    unsigned hb = (u + 0x7fffu + ((u >> 16) & 1u)) & 0xffff0000u;
    hi = (short)(hb >> 16);
    float r = v - __uint_as_float(hb);           // exact
    unsigned u2 = __float_as_uint(r);
    lo = (short)((u2 + 0x7fffu + ((u2 >> 16) & 1u)) >> 16);
}

// Pre-pass: split fc_w2 (256x256 f32, [k][n]) into pass-major fragment order:
// w2f[idx] with idx = pass*65536 + kc*4096 + hl*2048 + g*1024 + nloc*8 + i
// where k = kc*16 + g*8 + i, n = pass*128 + nloc, hl picks hi/lo bf16.
__global__ void split_w2_kernel(const float* __restrict__ w2, short* __restrict__ w2f) {
    const int idx  = blockIdx.x * 256 + threadIdx.x;   // 0 .. 131071
    const int i    = idx & 7;
    const int nloc = (idx >> 3) & 127;
    const int g    = (idx >> 10) & 1;
    const int hl   = (idx >> 11) & 1;
    const int kc   = (idx >> 12) & 15;
    const int pass = idx >> 16;
    const int k = kc * 16 + g * 8 + i;
    const int n = pass * 128 + nloc;
    short hi, lo;
    split_bf16(w2[k * 256 + n], hi, lo);
    w2f[idx] = hl ? lo : hi;
}

__global__ __launch_bounds__(256, 3)
void conv_mfma_kernel(const float* __restrict__ nf,     // (N, 32)
                      const int*   __restrict__ esrc,
                      const int*   __restrict__ edst,
                      const float* __restrict__ esh,    // (E, 4)
                      const float* __restrict__ escal,  // (E, 8)
                      const float* __restrict__ w1,     // (8, 256)
                      const short* __restrict__ w2f,    // pass-major frag hi/lo bf16
                      float* __restrict__ out)          // (N, 32)
{
    __shared__ __align__(16) char smem[45056];
    short* Bbuf  = (short*)smem;               // 2 x 4096 shorts (8 KB) double buffer
    float* wtile = (float*)smem;               // reused after K-loop: [128][34] f32
    float* xtile = (float*)(smem + 17408);     // [128][34] f32
    float* shtl  = (float*)(smem + 34816);     // [128][4]  f32
    float* w1l   = (float*)(smem + 36864);     // [8][256]  f32

    const int t  = threadIdx.x;
    const int l  = t & 63;
    const int wv = t >> 6;                     // wave id = 32-edge m-tile
    const int e0 = blockIdx.x * BM;

    // ---- prologue: stage x, sh, w1 into LDS
    {
        const int e = t >> 1, h2 = t & 1;
        const int src = esrc[e0 + e];
        const float* xp = nf + (size_t)src * 32 + h2 * 16;
        float* dp = xtile + e * WT + h2 * 16;
        #pragma unroll
        for (int q = 0; q < 4; ++q) {
            const float4 v4 = *reinterpret_cast<const float4*>(xp + q * 4);
            *reinterpret_cast<float2*>(dp + q * 4)     = make_float2(v4.x, v4.y);
            *reinterpret_cast<float2*>(dp + q * 4 + 2) = make_float2(v4.z, v4.w);
        }
        if (t < BM) {
            const float4 s4 = *reinterpret_cast<const float4*>(esh + (size_t)(e0 + t) * 4);
            *reinterpret_cast<float4*>(shtl + t * 4) = s4;
        }
        *reinterpret_cast<float4*>(w1l + t * 8)     = *reinterpret_cast<const float4*>(w1 + t * 8);
        *reinterpret_cast<float4*>(w1l + t * 8 + 4) = *reinterpret_cast<const float4*>(w1 + t * 8 + 4);
    }

    // ---- lane's escal row, pre-scaled by 0.5 (relu(0.5x) = 0.5*relu(x), exact)
    const int erow = e0 + wv * 32 + (l & 31);
    float es[8];
    {
        const float4 a = *reinterpret_cast<const float4*>(escal + (size_t)erow * 8);
        const float4 b = *reinterpret_cast<const float4*>(escal + (size_t)erow * 8 + 4);
        es[0]=a.x*0.5f; es[1]=a.y*0.5f; es[2]=a.z*0.5f; es[3]=a.w*0.5f;
        es[4]=b.x*0.5f; es[5]=b.y*0.5f; es[6]=b.z*0.5f; es[7]=b.w*0.5f;
    }
    __syncthreads();   // w1l / xtile / shtl resident

    // h-fragment build, truncation split (4 ops/value; |err| <= 2^-16 rel, and the
    // 3-term MFMA keeps both lo terms so only ~2^-24-level residue is dropped).
    // lane l: row = l&31, k = kc*16 + (l>>5)*8 + i  (same k-map as B read).
    auto compute_A = [&](int kc, frag_u& fh, frag_u& fl) {
        const int hb = kc * 16 + (l >> 5) * 8;
        float hv[8];
        #pragma unroll
        for (int i2 = 0; i2 < 8; ++i2) hv[i2] = 0.f;
        #pragma unroll
        for (int b = 0; b < 8; ++b) {
            const float4 wa  = *reinterpret_cast<const float4*>(w1l + b * 256 + hb);
            const float4 wb4 = *reinterpret_cast<const float4*>(w1l + b * 256 + hb + 4);
            hv[0] = fmaf(es[b], wa.x,  hv[0]);
            hv[1] = fmaf(es[b], wa.y,  hv[1]);
            hv[2] = fmaf(es[b], wa.z,  hv[2]);
            hv[3] = fmaf(es[b], wa.w,  hv[3]);
            hv[4] = fmaf(es[b], wb4.x, hv[4]);
            hv[5] = fmaf(es[b], wb4.y, hv[5]);
            hv[6] = fmaf(es[b], wb4.z, hv[6]);
            hv[7] = fmaf(es[b], wb4.w, hv[7]);
        }
        #pragma unroll
        for (int i2 = 0; i2 < 8; ++i2) {
            const float v = fmaxf(hv[i2], 0.f);
            const unsigned u = __float_as_uint(v);
            fh.s[i2] = (short)(u >> 16);                              // truncate hi
            const float r = v - __uint_as_float(u & 0xffff0000u);     // exact residual
            fl.s[i2] = (short)(__float_as_uint(r) >> 16);             // truncate lo
        }
    };

    const int el = t & 31, j = t >> 5;         // epilogue mapping (proven round 4)

    for (int pass = 0; pass < 2; ++pass) {
        const short* wp = w2f + pass * 65536;

        auto stage = [&](int kc, int buf) {
            const short* src = wp + kc * 4096;
            short* dst = Bbuf + buf * 4096;
            #pragma unroll
            for (int r = 0; r < 2; ++r) {
                __builtin_amdgcn_global_load_lds((glb_u32*)(src + r * 2048 + t * 8),
                                                 (lds_u32*)(dst + r * 2048 + t * 8),
                                                 16, 0, 0);
            }
        };

        f32x16 acc[4];
        #pragma unroll
        for (int nt = 0; nt < 4; ++nt)
            #pragma unroll
            for (int q = 0; q < 16; ++q) acc[nt][q] = 0.f;

        stage(0, 0);
        frag_u Ahi, Alo;
        compute_A(0, Ahi, Alo);
        __syncthreads();

        const int bbase = (l >> 5) * 1024 + (l & 31) * 8;   // shorts

        for (int kc = 0; kc < NKC; ++kc) {
            const int cur = kc & 1;
            if (kc + 1 < NKC) stage(kc + 1, cur ^ 1);

            frag_u Anh, Anl;
            if (kc + 1 < NKC) compute_A(kc + 1, Anh, Anl);

            const short* Bb = Bbuf + cur * 4096;
            #pragma unroll
            for (int nt = 0; nt < 4; ++nt) {
                frag_u Bhi, Blo;
                Bhi.s = *reinterpret_cast<const s16x8*>(Bb + bbase + nt * 256);
                Blo.s = *reinterpret_cast<const s16x8*>(Bb + 2048 + bbase + nt * 256);
                acc[nt] = __builtin_amdgcn_mfma_f32_32x32x16_bf16(Ahi.b, Bhi.b, acc[nt], 0, 0, 0);
                acc[nt] = __builtin_amdgcn_mfma_f32_32x32x16_bf16(Alo.b, Bhi.b, acc[nt], 0, 0, 0);
                acc[nt] = __builtin_amdgcn_mfma_f32_32x32x16_bf16(Ahi.b, Blo.b, acc[nt], 0, 0, 0);
            }

            if (kc + 1 < NKC) { Ahi = Anh; Alo = Anl; }
            __syncthreads();   // next buffer resident + all reads of cur done
        }

        // ---- epilogue for this pass (4 rounds; wave r dumps its 32-edge m-tile)
        for (int round = 0; round < 4; ++round) {
            if (wv == round) {
                #pragma unroll
                for (int nt = 0; nt < 4; ++nt) {
                    float* bp = wtile + (nt * 32 + (l & 31)) * WT + (l >> 5) * 4;
                    #pragma unroll
                    for (int q = 0; q < 4; ++q) {
                        *reinterpret_cast<float2*>(bp + q * 8)     = make_float2(acc[nt][q*4+0], acc[nt][q*4+1]);
                        *reinterpret_cast<float2*>(bp + q * 8 + 2) = make_float2(acc[nt][q*4+2], acc[nt][q*4+3]);
                    }
                }
            }
            __syncthreads();

            const int eg = round * 32 + el;
            const float* xr = xtile + eg * WT;
            const float s2  = shtl[eg * 4 + 0];
            const float v20 = shtl[eg * 4 + 1];
            const float v21 = shtl[eg * 4 + 2];
            const float v22 = shtl[eg * 4 + 3];
            const int dst = edst[e0 + eg];
            float* op = out + (size_t)dst * 32;

            if (pass == 0) {
                // cols 0..127 = groups 0 (s1*s2 . w0) and 1 (dv . w1) -> out_s
                float P0 = 0.f, P1 = 0.f;
                #pragma unroll
                for (int u = 0; u < 8; ++u) {
                    const float s1 = xr[u];
                    const float a0 = xr[8 + u * 3 + 0];
                    const float a1 = xr[8 + u * 3 + 1];
                    const float a2 = xr[8 + u * 3 + 2];
                    const float dv = a0 * v20 + a1 * v21 + a2 * v22;
                    P0 = fmaf(s1, wtile[(     u * 8 + j) * WT + el], P0);
                    P1 = fmaf(dv, wtile[(64 + u * 8 + j) * WT + el], P1);
                }
                atomicAdd(op + j, CS * (s2 * P0 + INV_SQRT3_C * P1));
            } else {
                // cols 128..255 = groups 2 (s1 . w2 x v2) and 3 (v1*s2 . w3) -> out_v
                float Q = 0.f, R0 = 0.f, R1 = 0.f, R2 = 0.f;
                #pragma unroll
                for (int u = 0; u < 8; ++u) {
                    const float s1 = xr[u];
                    const float a0 = xr[8 + u * 3 + 0];
                    const float a1 = xr[8 + u * 3 + 1];
                    const float a2 = xr[8 + u * 3 + 2];
                    const float w2v = wtile[(     u * 8 + j) * WT + el];
                    const float w3v = wtile[(64 + u * 8 + j) * WT + el];
                    Q  = fmaf(s1, w2v, Q);
                    R0 = fmaf(a0, w3v, R0);
                    R1 = fmaf(a1, w3v, R1);
                    R2 = fmaf(a2, w3v, R2);
                }
                atomicAdd(op + 8 + j * 3 + 0, CS * (Q * v20 + s2 * R0));
                atomicAdd(op + 8 + j * 3 + 1, CS * (Q * v21 + s2 * R1));
                atomicAdd(op + 8 + j * 3 + 2, CS * (Q * v22 + s2 * R2));
            }
            // LATENT-RACE FIX (was `if (round < 3)`): round-3 contraction reads
            // wtile (= Bbuf overlay); the next pass's stage(0,0) async-writes that
            // region. Unconditional barrier orders read -> async write.
            __syncthreads();
        }
    }
}

extern "C" void kernel_launch(void* const* d_in, const int* in_sizes, int n_in,
                              void* d_out, int out_size, void* d_ws, size_t ws_size,
                              hipStream_t stream) {
    const float* nf    = (const float*)d_in[0];
    const int*   esrc  = (const int*)d_in[1];
    const int*   edst  = (const int*)d_in[2];
    const float* esh   = (const float*)d_in[3];
    const float* escal = (const float*)d_in[4];
    const float* w1    = (const float*)d_in[5];
    const float* w2    = (const float*)d_in[6];
    float* out  = (float*)d_out;
    short* w2f  = (short*)d_ws;     // 256 KB

    hipMemsetAsync(d_out, 0, (size_t)out_size * sizeof(float), stream);
    split_w2_kernel<<<512, 256, 0, stream>>>(w2, w2f);
    conv_mfma_kernel<<<E_TOTAL / BM, 256, 0, stream>>>(
        nf, esrc, edst, esh, escal, w1, w2f, out);
}

// Round 9
// 541.760 us; speedup vs baseline: 2.0943x; 1.6607x over previous
//
#include <hip/hip_runtime.h>
#include <hip/hip_bf16.h>

#define E_TOTAL 800000
#define BM 128            // edges per block
#define NKC 16            // K chunks of 16 (K = 256)
#define WT 34             // wtile/xtile stride in floats

static constexpr float INV_SQRT3_C = 0.57735026918962576f;
// CS = A_SCALAR * (1/16 fc_w2 scale) * (0.25 final scale); A_VECTOR*INV_SQRT3 == A_SCALAR
static constexpr float CS = 0.0013810679320049758f;

typedef __attribute__((ext_vector_type(8)))  __bf16 bf16x8;
typedef __attribute__((ext_vector_type(8)))  short  s16x8;
typedef __attribute__((ext_vector_type(16))) float  f32x16;

union frag_u { s16x8 s; bf16x8 b; };

typedef __attribute__((address_space(3))) unsigned int lds_u32;
typedef const __attribute__((address_space(1))) unsigned int glb_u32;

__device__ __forceinline__ void split_bf16(float v, short& hi, short& lo) {
    unsigned u  = __float_as_uint(v);
    unsigned hb = (u + 0x7fffu + ((u >> 16) & 1u)) & 0xffff0000u;
    hi = (short)(hb >> 16);
    float r = v - __uint_as_float(hb);           // exact
    unsigned u2 = __float_as_uint(r);
    lo = (short)((u2 + 0x7fffu + ((u2 >> 16) & 1u)) >> 16);
}

// Pre-pass: split fc_w2 (256x256 f32, [k][n]) into pass-major fragment order:
// w2f[idx] with idx = pass*65536 + kc*4096 + hl*2048 + g*1024 + nloc*8 + i
// where k = kc*16 + g*8 + i, n = pass*128 + nloc, hl picks hi/lo bf16.
__global__ void split_w2_kernel(const float* __restrict__ w2, short* __restrict__ w2f) {
    const int idx  = blockIdx.x * 256 + threadIdx.x;   // 0 .. 131071
    const int i    = idx & 7;
    const int nloc = (idx >> 3) & 127;
    const int g    = (idx >> 10) & 1;
    const int hl   = (idx >> 11) & 1;
    const int kc   = (idx >> 12) & 15;
    const int pass = idx >> 16;
    const int k = kc * 16 + g * 8 + i;
    const int n = pass * 128 + nloc;
    short hi, lo;
    split_bf16(w2[k * 256 + n], hi, lo);
    w2f[idx] = hl ? lo : hi;
}

__global__ __launch_bounds__(256, 3)
void conv_mfma_kernel(const float* __restrict__ nf,     // (N, 32)
                      const int*   __restrict__ esrc,
                      const int*   __restrict__ edst,
                      const float* __restrict__ esh,    // (E, 4)
                      const float* __restrict__ escal,  // (E, 8)
                      const float* __restrict__ w1,     // (8, 256)
                      const short* __restrict__ w2f,    // pass-major frag hi/lo bf16
                      float* __restrict__ out)          // (N, 32)
{
    __shared__ __align__(16) char smem[45056];
    short* Bbuf  = (short*)smem;               // 2 x 4096 shorts (8 KB) double buffer
    float* wtile = (float*)smem;               // reused after K-loop: [128][34] f32
    float* xtile = (float*)(smem + 17408);     // [128][34] f32
    float* shtl  = (float*)(smem + 34816);     // [128][4]  f32
    float* w1l   = (float*)(smem + 36864);     // [8][256]  f32

    const int t  = threadIdx.x;
    const int l  = t & 63;
    const int wv = t >> 6;                     // wave id = 32-edge m-tile
    const int e0 = blockIdx.x * BM;

    // ---- prologue: stage x, sh, w1 into LDS
    {
        const int e = t >> 1, h2 = t & 1;
        const int src = esrc[e0 + e];
        const float* xp = nf + (size_t)src * 32 + h2 * 16;
        float* dp = xtile + e * WT + h2 * 16;
        #pragma unroll
        for (int q = 0; q < 4; ++q) {
            const float4 v4 = *reinterpret_cast<const float4*>(xp + q * 4);
            *reinterpret_cast<float2*>(dp + q * 4)     = make_float2(v4.x, v4.y);
            *reinterpret_cast<float2*>(dp + q * 4 + 2) = make_float2(v4.z, v4.w);
        }
        if (t < BM) {
            const float4 s4 = *reinterpret_cast<const float4*>(esh + (size_t)(e0 + t) * 4);
            *reinterpret_cast<float4*>(shtl + t * 4) = s4;
        }
        *reinterpret_cast<float4*>(w1l + t * 8)     = *reinterpret_cast<const float4*>(w1 + t * 8);
        *reinterpret_cast<float4*>(w1l + t * 8 + 4) = *reinterpret_cast<const float4*>(w1 + t * 8 + 4);
    }

    // ---- lane's escal row, pre-scaled by 0.5 (relu(0.5x) = 0.5*relu(x), exact)
    const int erow = e0 + wv * 32 + (l & 31);
    float es[8];
    {
        const float4 a = *reinterpret_cast<const float4*>(escal + (size_t)erow * 8);
        const float4 b = *reinterpret_cast<const float4*>(escal + (size_t)erow * 8 + 4);
        es[0]=a.x*0.5f; es[1]=a.y*0.5f; es[2]=a.z*0.5f; es[3]=a.w*0.5f;
        es[4]=b.x*0.5f; es[5]=b.y*0.5f; es[6]=b.z*0.5f; es[7]=b.w*0.5f;
    }
    __syncthreads();   // w1l / xtile / shtl resident

    // h-fragment build, truncation split (4 ops/value; |err| <= 2^-16 rel, and the
    // 3-term MFMA keeps both lo terms so only ~2^-24-level residue is dropped).
    // lane l: row = l&31, k = kc*16 + (l>>5)*8 + i  (same k-map as B read).
    auto compute_A = [&](int kc, frag_u& fh, frag_u& fl) {
        const int hb = kc * 16 + (l >> 5) * 8;
        float hv[8];
        #pragma unroll
        for (int i2 = 0; i2 < 8; ++i2) hv[i2] = 0.f;
        #pragma unroll
        for (int b = 0; b < 8; ++b) {
            const float4 wa  = *reinterpret_cast<const float4*>(w1l + b * 256 + hb);
            const float4 wb4 = *reinterpret_cast<const float4*>(w1l + b * 256 + hb + 4);
            hv[0] = fmaf(es[b], wa.x,  hv[0]);
            hv[1] = fmaf(es[b], wa.y,  hv[1]);
            hv[2] = fmaf(es[b], wa.z,  hv[2]);
            hv[3] = fmaf(es[b], wa.w,  hv[3]);
            hv[4] = fmaf(es[b], wb4.x, hv[4]);
            hv[5] = fmaf(es[b], wb4.y, hv[5]);
            hv[6] = fmaf(es[b], wb4.z, hv[6]);
            hv[7] = fmaf(es[b], wb4.w, hv[7]);
        }
        #pragma unroll
        for (int i2 = 0; i2 < 8; ++i2) {
            const float v = fmaxf(hv[i2], 0.f);
            const unsigned u = __float_as_uint(v);
            fh.s[i2] = (short)(u >> 16);                              // truncate hi
            const float r = v - __uint_as_float(u & 0xffff0000u);     // exact residual
            fl.s[i2] = (short)(__float_as_uint(r) >> 16);             // truncate lo
        }
    };

    // ROUND-9 FIX: round 8 shipped round-3's scatter mapping (el=t&31, j=t>>5) by
    // mistake -> 32 distinct output rows per wave atomic, WRITE_SIZE 516 MB.
    // This is round 4's actual coalesced mapping: 8 rows x 8 cols per wave.
    const int el = t >> 3;       // epilogue edge-local (0..31 across the block)
    const int j  = t & 7;        // output column group

    for (int pass = 0; pass < 2; ++pass) {
        const short* wp = w2f + pass * 65536;

        auto stage = [&](int kc, int buf) {
            const short* src = wp + kc * 4096;
            short* dst = Bbuf + buf * 4096;
            #pragma unroll
            for (int r = 0; r < 2; ++r) {
                __builtin_amdgcn_global_load_lds((glb_u32*)(src + r * 2048 + t * 8),
                                                 (lds_u32*)(dst + r * 2048 + t * 8),
                                                 16, 0, 0);
            }
        };

        f32x16 acc[4];
        #pragma unroll
        for (int nt = 0; nt < 4; ++nt)
            #pragma unroll
            for (int q = 0; q < 16; ++q) acc[nt][q] = 0.f;

        stage(0, 0);
        frag_u Ahi, Alo;
        compute_A(0, Ahi, Alo);
        __syncthreads();

        const int bbase = (l >> 5) * 1024 + (l & 31) * 8;   // shorts

        for (int kc = 0; kc < NKC; ++kc) {
            const int cur = kc & 1;
            if (kc + 1 < NKC) stage(kc + 1, cur ^ 1);

            frag_u Anh, Anl;
            if (kc + 1 < NKC) compute_A(kc + 1, Anh, Anl);

            const short* Bb = Bbuf + cur * 4096;
            #pragma unroll
            for (int nt = 0; nt < 4; ++nt) {
                frag_u Bhi, Blo;
                Bhi.s = *reinterpret_cast<const s16x8*>(Bb + bbase + nt * 256);
                Blo.s = *reinterpret_cast<const s16x8*>(Bb + 2048 + bbase + nt * 256);
                acc[nt] = __builtin_amdgcn_mfma_f32_32x32x16_bf16(Ahi.b, Bhi.b, acc[nt], 0, 0, 0);
                acc[nt] = __builtin_amdgcn_mfma_f32_32x32x16_bf16(Alo.b, Bhi.b, acc[nt], 0, 0, 0);
                acc[nt] = __builtin_amdgcn_mfma_f32_32x32x16_bf16(Ahi.b, Blo.b, acc[nt], 0, 0, 0);
            }

            if (kc + 1 < NKC) { Ahi = Anh; Alo = Anl; }
            __syncthreads();   // next buffer resident + all reads of cur done
        }

        // ---- epilogue for this pass (4 rounds; wave r dumps its 32-edge m-tile)
        for (int round = 0; round < 4; ++round) {
            if (wv == round) {
                #pragma unroll
                for (int nt = 0; nt < 4; ++nt) {
                    float* bp = wtile + (nt * 32 + (l & 31)) * WT + (l >> 5) * 4;
                    #pragma unroll
                    for (int q = 0; q < 4; ++q) {
                        *reinterpret_cast<float2*>(bp + q * 8)     = make_float2(acc[nt][q*4+0], acc[nt][q*4+1]);
                        *reinterpret_cast<float2*>(bp + q * 8 + 2) = make_float2(acc[nt][q*4+2], acc[nt][q*4+3]);
                    }
                }
            }
            __syncthreads();

            const int eg = round * 32 + el;
            const float* xr = xtile + eg * WT;
            const float s2  = shtl[eg * 4 + 0];
            const float v20 = shtl[eg * 4 + 1];
            const float v21 = shtl[eg * 4 + 2];
            const float v22 = shtl[eg * 4 + 3];
            const int dst = edst[e0 + eg];
            float* op = out + (size_t)dst * 32;

            if (pass == 0) {
                // cols 0..127 = groups 0 (s1*s2 . w0) and 1 (dv . w1) -> out_s
                float P0 = 0.f, P1 = 0.f;
                #pragma unroll
                for (int u = 0; u < 8; ++u) {
                    const float s1 = xr[u];
                    const float a0 = xr[8 + u * 3 + 0];
                    const float a1 = xr[8 + u * 3 + 1];
                    const float a2 = xr[8 + u * 3 + 2];
                    const float dv = a0 * v20 + a1 * v21 + a2 * v22;
                    P0 = fmaf(s1, wtile[(     u * 8 + j) * WT + el], P0);
                    P1 = fmaf(dv, wtile[(64 + u * 8 + j) * WT + el], P1);
                }
                atomicAdd(op + j, CS * (s2 * P0 + INV_SQRT3_C * P1));
            } else {
                // cols 128..255 = groups 2 (s1 . w2 x v2) and 3 (v1*s2 . w3) -> out_v
                float Q = 0.f, R0 = 0.f, R1 = 0.f, R2 = 0.f;
                #pragma unroll
                for (int u = 0; u < 8; ++u) {
                    const float s1 = xr[u];
                    const float a0 = xr[8 + u * 3 + 0];
                    const float a1 = xr[8 + u * 3 + 1];
                    const float a2 = xr[8 + u * 3 + 2];
                    const float w2v = wtile[(     u * 8 + j) * WT + el];
                    const float w3v = wtile[(64 + u * 8 + j) * WT + el];
                    Q  = fmaf(s1, w2v, Q);
                    R0 = fmaf(a0, w3v, R0);
                    R1 = fmaf(a1, w3v, R1);
                    R2 = fmaf(a2, w3v, R2);
                }
                atomicAdd(op + 8 + j * 3 + 0, CS * (Q * v20 + s2 * R0));
                atomicAdd(op + 8 + j * 3 + 1, CS * (Q * v21 + s2 * R1));
                atomicAdd(op + 8 + j * 3 + 2, CS * (Q * v22 + s2 * R2));
            }
            // Unconditional: round-3 contraction reads wtile (= Bbuf overlay); the
            // next pass's stage(0,0) async-writes that region. Barrier orders them.
            __syncthreads();
        }
    }
}

extern "C" void kernel_launch(void* const* d_in, const int* in_sizes, int n_in,
                              void* d_out, int out_size, void* d_ws, size_t ws_size,
                              hipStream_t stream) {
    const float* nf    = (const float*)d_in[0];
    const int*   esrc  = (const int*)d_in[1];
    const int*   edst  = (const int*)d_in[2];
    const float* esh   = (const float*)d_in[3];
    const float* escal = (const float*)d_in[4];
    const float* w1    = (const float*)d_in[5];
    const float* w2    = (const float*)d_in[6];
    float* out  = (float*)d_out;
    short* w2f  = (short*)d_ws;     // 256 KB

    hipMemsetAsync(d_out, 0, (size_t)out_size * sizeof(float), stream);
    split_w2_kernel<<<512, 256, 0, stream>>>(w2, w2f);
    conv_mfma_kernel<<<E_TOTAL / BM, 256, 0, stream>>>(
        nf, esrc, edst, esh, escal, w1, w2f, out);
}